// Round 1
// baseline (186.460 us; speedup 1.0000x reference)
//
#include <hip/hip_runtime.h>
#include <hip/hip_bf16.h>
#include <math.h>

#define B_N 512
#define C_N 100000
#define CPAD 100032          // padded to multiple of 64
#define D_N 128
#define NCHUNK (CPAD / 64)   // 1563
#define K5_BLOCKS (CPAD / 4) // 25008
#define K6_GX 256
#define K6_GY 2
#define K6_BLOCKS (K6_GX * K6_GY)
// each proxy pad row (zero vector) contributes exp(-18) to every row's sumexp
#define PAD_CORR (32.0f * 1.522998e-8f)

typedef short short8 __attribute__((ext_vector_type(8)));
typedef float f32x4 __attribute__((ext_vector_type(4)));

__device__ __forceinline__ unsigned short f2bf(float f) {
  unsigned int u = __float_as_uint(f);
  u += 0x7fffu + ((u >> 16) & 1u);
  return (unsigned short)(u >> 16);
}

__device__ __forceinline__ void gl_lds16(const void* g, void* l) {
  __builtin_amdgcn_global_load_lds(
      (const __attribute__((address_space(1))) void*)g,
      (__attribute__((address_space(3))) void*)l, 16, 0, 0);
}

template <int NT>
__device__ __forceinline__ float block_reduce_sum(float v, float* red) {
  int t = threadIdx.x;
  __syncthreads();
  red[t] = v;
  __syncthreads();
#pragma unroll
  for (int s = NT / 2; s > 0; s >>= 1) {
    if (t < s) red[t] += red[t + s];
    __syncthreads();
  }
  return red[0];
}

// kA: fused proxy-normalize (blocks [0,K5_BLOCKS)) + X-normalize/Pb/diag.
// Also zeroes kB's arrive counter (ctrs[64]); X2 global state is gone (kB
// keeps the attention row fully local now).
__global__ __launch_bounds__(256) void kA(const float* __restrict__ X,
                                          const float* __restrict__ proxies,
                                          const int* __restrict__ T,
                                          float* __restrict__ Xn, float* __restrict__ Pb,
                                          float* __restrict__ diagv,
                                          unsigned short* __restrict__ Pnb,
                                          int* __restrict__ ctrs) {
  int bid = blockIdx.x;
  int t = threadIdx.x;
  if (bid < K5_BLOCKS) {
    int lane = t & 63;
    int row = bid * 4 + (t >> 6);
    float2 v = make_float2(0.f, 0.f);
    if (row < C_N) v = *(const float2*)(proxies + (size_t)row * D_N + 2 * lane);
    float ss = v.x * v.x + v.y * v.y;
#pragma unroll
    for (int off = 1; off < 64; off <<= 1) ss += __shfl_xor(ss, off);
    float inv = 1.f / fmaxf(sqrtf(ss), 1e-12f);
    unsigned short a = f2bf(v.x * inv), b = f2bf(v.y * inv);
    unsigned int pk = (unsigned int)a | ((unsigned int)b << 16);
    *(unsigned int*)(Pnb + (size_t)row * D_N + 2 * lane) = pk;  // pad rows -> exact zeros
  } else {
    __shared__ float red[256];
    int b = bid - K5_BLOCKS;
    bool act = t < D_N;
    float v = act ? X[b * D_N + t] : 0.f;
    float ss = block_reduce_sum<256>(v * v, red);
    float xn = v / fmaxf(sqrtf(ss), 1e-12f);
    if (act) Xn[b * D_N + t] = xn;
    int row = T[b];
    float p = act ? proxies[(size_t)row * D_N + t] : 0.f;
    float ss2 = block_reduce_sum<256>(p * p, red);
    float pn = p / fmaxf(sqrtf(ss2), 1e-12f);
    if (act) Pb[b * D_N + t] = pn;
    float d = block_reduce_sum<256>(pn * xn, red);
    if (t == 0) {
      diagv[b] = d;
      if (b == 0) ctrs[64] = 0;  // kB arrive counter, own cache line
    }
  }
}

// kB: fused k3+k4a+k4b. Block b owns attention row b end-to-end:
//   phase1: A[b,:] in LDS (2 KB), row sum S[b] -> device-coherent publish
//   grid barrier: the only cross-block data is the 512-float S vector.
//     __launch_bounds__(256,2) + grid=512=256CUx2 guarantees co-residency;
//     ordering = coherent store -> s_waitcnt(0) -> arrive atomic (k6's proven
//     pattern); readers use agent-scope atomic loads (bypass possibly-stale L2).
//   phase2: aw[k]=A[b,k]/(S[k]+eps); X2row = Xn[b,:] + aw @ Xn  (local)
//   phase3: Xs=3*l2norm(X2row) -> Xsb bf16, lossT[b], zero k6 state.
// Kills the A (1MB) and X2 (atomics) global round-trips + two launch gaps.
__global__ __launch_bounds__(256, 2) void kB_att(const float* __restrict__ Xn,
                                                 const float* __restrict__ Pb,
                                                 const float* __restrict__ diagv,
                                                 float* __restrict__ Sg,
                                                 unsigned short* __restrict__ Xsb,
                                                 float* __restrict__ lossT,
                                                 float* __restrict__ sumexpP,
                                                 int* __restrict__ ctrs) {
  __shared__ float xb[128], pbv[128];
  __shared__ float aL[512];
  __shared__ float red[256];
  int b = blockIdx.x, t = threadIdx.x;
  if (t < 128) {
    xb[t] = Xn[b * D_N + t];
    pbv[t] = Pb[b * D_N + t];
  }
  __syncthreads();

  // ---- phase 1: attention row + row sum (same arithmetic as old k3) ----
  float rs = 0.f;
  for (int k = t; k < B_N; k += 256) {
    const float4* xr = (const float4*)(Xn + (size_t)k * D_N);
    float d1 = 0.f, d2 = 0.f;
#pragma unroll
    for (int i = 0; i < 32; i++) {
      float4 v = xr[i];
      d1 += pbv[4 * i] * v.x + pbv[4 * i + 1] * v.y + pbv[4 * i + 2] * v.z + pbv[4 * i + 3] * v.w;
      d2 += xb[4 * i] * v.x + xb[4 * i + 1] * v.y + xb[4 * i + 2] * v.z + xb[4 * i + 3] * v.w;
    }
    float a = fmaxf(0.5f * (d1 + diagv[k]), 0.f) + fmaxf(d2, 0.f);
    aL[k] = a;
    rs += a;
  }
  rs = block_reduce_sum<256>(rs, red);

  // ---- publish S[b]; software grid barrier on arrive counter ----
  if (t == 0) {
    __hip_atomic_store(&Sg[b], rs, __ATOMIC_RELAXED, __HIP_MEMORY_SCOPE_AGENT);
    __builtin_amdgcn_s_waitcnt(0);  // S store at coherence point before arrive
    atomicAdd(&ctrs[64], 1);
    while (__hip_atomic_load(&ctrs[64], __ATOMIC_RELAXED, __HIP_MEMORY_SCOPE_AGENT) < B_N)
      __builtin_amdgcn_s_sleep(2);
  }
  __syncthreads();
  __builtin_amdgcn_sched_barrier(0);

  // ---- phase 2: column-normalize local row, matvec against Xn ----
  for (int k = t; k < B_N; k += 256) {
    float sv = __hip_atomic_load(&Sg[k], __ATOMIC_RELAXED, __HIP_MEMORY_SCOPE_AGENT);
    aL[k] = aL[k] / (sv + 1e-5f);
  }
  __syncthreads();
  int d = t & 127, h = t >> 7;
  const float* xp = Xn + (size_t)(256 * h) * D_N + d;
  float acc0 = 0.f, acc1 = 0.f;
#pragma unroll 4
  for (int kk = 0; kk < 256; kk += 2) {
    acc0 = fmaf(aL[256 * h + kk], xp[(size_t)kk * D_N], acc0);
    acc1 = fmaf(aL[256 * h + kk + 1], xp[(size_t)(kk + 1) * D_N], acc1);
  }
  red[t] = acc0 + acc1;
  __syncthreads();
  float x2 = (t < 128) ? (xb[t] + red[t] + red[t + 128]) : 0.f;

  // ---- phase 3: renorm + Xsb/lossT epilogue (old k4b) ----
  float ss = block_reduce_sum<256>(x2 * x2, red);
  float xs = 3.f * x2 / fmaxf(sqrtf(ss), 1e-12f);
  if (t < 128) Xsb[b * D_N + t] = f2bf(xs);
  float dt = block_reduce_sum<256>((t < 128) ? xs * pbv[t] : 0.f, red);
  if (t == 0) {
    lossT[b] = fmaxf(18.f - 6.f * dt, 0.f);
    sumexpP[b * 16] = 0.f;
    if (b == 0) ctrs[32] = 0;  // k6 arrive counter, own cache line
  }
}

// K6: Dm[b,c] = max(18 - 6*dot(Xs[b], Pn[c]), 0); sumexp[b] += sum_c exp(-Dm)
// grid (256,2), block 256, tile 256 b x 64 c (4 m-tiles/wave). Epilogue now
// uses exp2 with the log2e folded into the existing FMA (one VALU op fewer
// per element in the VALU-heaviest loop).
__global__ __launch_bounds__(256, 2) void k6_big(const unsigned short* __restrict__ Pnb,
                                                 const unsigned short* __restrict__ Xsb,
                                                 float* __restrict__ sumexpP,
                                                 const float* __restrict__ lossT,
                                                 int* __restrict__ ctrs,
                                                 float* __restrict__ out) {
  __shared__ __align__(16) unsigned short sP[2][64 * 128];  // 2 x 16 KB, XOR-swizzled
  __shared__ float redf[256];
  __shared__ int sLast;
  const int t = threadIdx.x;
  const int w = t >> 6;
  const int lane = t & 63;
  const int lc = lane & 15;
  const int q = lane >> 4;
  const int b0 = blockIdx.y * 256;

  // A-fragments once from global bf16 Xsb: wave w owns m-rows 64w..64w+63
  short8 afr[4][4];
#pragma unroll
  for (int mt = 0; mt < 4; mt++)
#pragma unroll
    for (int ks = 0; ks < 4; ks++)
      afr[mt][ks] = *(const short8*)(Xsb + (size_t)(b0 + 64 * w + 16 * mt + lc) * D_N +
                                     ks * 32 + q * 8);

  float pe[4][4];
#pragma unroll
  for (int mt = 0; mt < 4; mt++)
#pragma unroll
    for (int r = 0; r < 4; r++) pe[mt][r] = 0.f;

  // staging: wave w stages rows 16w..16w+15 (4 instr x 1024 B); dest granule
  // (R,P) holds global granule g = P ^ (R&15) (bank swizzle, DMA-compatible).
  const int rR = 16 * w + (lane >> 4);
  const int gsrc0 = (lane & 15);
#define STAGE(c0_, buf_)                                                              \
  {                                                                                   \
    _Pragma("unroll") for (int j = 0; j < 4; j++) {                                   \
      int R = rR + 4 * j;                                                             \
      int g = gsrc0 ^ ((R)&15);                                                       \
      gl_lds16(Pnb + (((size_t)(c0_) + R) << 7) + (g << 3),                           \
               &sP[buf_][w * 2048 + j * 512]);                                        \
    }                                                                                 \
  }

  int cc = blockIdx.x;
  STAGE(cc * 64, 0);
  int buf = 0;
  while (true) {
    int nc = cc + gridDim.x;
    if (nc < NCHUNK) STAGE(nc * 64, buf ^ 1);  // issue next-buffer DMA early
    __builtin_amdgcn_sched_barrier(0);         // keep stage issue above the wait
    __builtin_amdgcn_s_waitcnt(0x0F74);        // vmcnt<=4: current buf landed, next in flight
    __builtin_amdgcn_s_barrier();              // rendezvous (NO vmcnt(0) drain)
    __builtin_amdgcn_sched_barrier(0);         // no ds_read hoist above barrier

    f32x4 acc[4][4];
#pragma unroll
    for (int mt = 0; mt < 4; mt++)
#pragma unroll
      for (int nt = 0; nt < 4; nt++) acc[mt][nt] = (f32x4){0.f, 0.f, 0.f, 0.f};

#pragma unroll
    for (int ks = 0; ks < 4; ks++) {
      short8 bfr[4];
#pragma unroll
      for (int nt = 0; nt < 4; nt++) {
        int R = 16 * nt + lc;
        int g = (ks * 4 + q) ^ lc;  // R&15 == lc
        bfr[nt] = *(const short8*)(&sP[buf][R * 128 + (g << 3)]);
      }
#pragma unroll
      for (int nt = 0; nt < 4; nt++)
#pragma unroll
        for (int mt = 0; mt < 4; mt++)
          acc[mt][nt] = __builtin_amdgcn_mfma_f32_16x16x32_bf16(afr[mt][ks], bfr[nt],
                                                                acc[mt][nt], 0, 0, 0);
    }

    // epilogue: no bounds predicate — pad rows are zero vectors, corrected at end.
    // exp(min(6a-18,0)) == exp2(min((6*log2e)a - 18*log2e, 0)) — log2e folded in FMA.
#pragma unroll
    for (int mt = 0; mt < 4; mt++)
#pragma unroll
      for (int nt = 0; nt < 4; nt++) {
        f32x4 a = acc[mt][nt];
#pragma unroll
        for (int r = 0; r < 4; r++)
          pe[mt][r] += __builtin_amdgcn_exp2f(
              fminf(__fmaf_rn(8.65617024533378f, a[r], -25.9685107360013f), 0.f));
      }

    if (nc >= NCHUNK) break;
    __builtin_amdgcn_sched_barrier(0);  // ds_reads stay above the release barrier
    __builtin_amdgcn_s_barrier();       // all waves done reading buf -> restage safe
    cc = nc;
    buf ^= 1;
  }

  // reduce over 16 col-lanes; one padded atomic per row
#pragma unroll
  for (int mt = 0; mt < 4; mt++) {
#pragma unroll
    for (int r = 0; r < 4; r++) {
      float p = pe[mt][r];
      p += __shfl_xor(p, 1);
      p += __shfl_xor(p, 2);
      p += __shfl_xor(p, 4);
      p += __shfl_xor(p, 8);
      if (lc == 0) {
        int rb = b0 + 64 * w + 16 * mt + 4 * q + r;
        atomicAdd(&sumexpP[rb * 16], p);
      }
    }
  }

  // fused k7: last block to arrive reduces the loss. Atomics complete at the
  // device coherence point; ordering needs only vmcnt(0) (NO threadfence --
  // agent fences emit L2 writeback/invalidate, measured ~46 us over the grid).
  __builtin_amdgcn_s_waitcnt(0);
  if (t == 0) sLast = atomicAdd(&ctrs[32], 1);
  __syncthreads();
  if (sLast == K6_BLOCKS - 1) {
    float v = 0.f;
#pragma unroll
    for (int i = 0; i < 2; i++) {
      int b = t + 256 * i;
      float se = __hip_atomic_load(&sumexpP[b * 16], __ATOMIC_RELAXED,
                                   __HIP_MEMORY_SCOPE_AGENT);
      v += lossT[b] + logf(se - PAD_CORR);
    }
    float s = block_reduce_sum<256>(v, redf);
    if (t == 0) out[0] = s * (1.0f / 512.0f);
  }
}

extern "C" void kernel_launch(void* const* d_in, const int* in_sizes, int n_in,
                              void* d_out, int out_size, void* d_ws, size_t ws_size,
                              hipStream_t stream) {
  const float* X = (const float*)d_in[0];
  const int* T = (const int*)d_in[2];
  const float* proxies = (const float*)d_in[3];
  float* out = (float*)d_out;

  char* ws = (char*)d_ws;
  unsigned short* Pnb = (unsigned short*)ws;               // CPAD*128 bf16 = 25.6 MB
  float* Xn = (float*)(ws + (size_t)CPAD * D_N * 2);       // 512*128
  float* Pb = Xn + B_N * D_N;                              // 512*128
  float* X2 = Pb + B_N * D_N;                              // 512*128 (unused, layout kept)
  float* dg = X2 + B_N * D_N;                              // 512
  float* S = dg + B_N;                                     // 512 (device-coherent)
  float* lossT = S + B_N;                                  // 512
  float* sumexpP = lossT + B_N;                            // 512*16 (line-padded)
  unsigned short* Xsb = (unsigned short*)(sumexpP + B_N * 16);  // 512*128 bf16
  float* A = (float*)(Xsb + B_N * D_N);                    // 512*512 (unused, layout kept)
  int* ctrs = (int*)(A + B_N * B_N);                       // [32]=k6 arrive, [64]=kB arrive

  kA<<<K5_BLOCKS + B_N, 256, 0, stream>>>(X, proxies, T, Xn, Pb, dg, Pnb, ctrs);
  kB_att<<<B_N, 256, 0, stream>>>(Xn, Pb, dg, S, Xsb, lossT, sumexpP, ctrs);
  k6_big<<<dim3(K6_GX, K6_GY), 256, 0, stream>>>(Pnb, Xsb, sumexpP, lossT, ctrs, out);
}

// Round 2
// 152.932 us; speedup vs baseline: 1.2192x; 1.2192x over previous
//
#include <hip/hip_runtime.h>
#include <hip/hip_bf16.h>
#include <math.h>

#define B_N 512
#define C_N 100000
#define CPAD 100032          // padded to multiple of 64
#define D_N 128
#define NCHUNK (CPAD / 64)   // 1563
#define K5_BLOCKS (CPAD / 4) // 25008
#define K6_GX 256
#define K6_GY 2
#define K6_BLOCKS (K6_GX * K6_GY)
// each proxy pad row (zero vector) contributes exp(-18) to every row's sumexp
#define PAD_CORR (32.0f * 1.522998e-8f)

typedef short short8 __attribute__((ext_vector_type(8)));
typedef float f32x4 __attribute__((ext_vector_type(4)));

__device__ __forceinline__ unsigned short f2bf(float f) {
  unsigned int u = __float_as_uint(f);
  u += 0x7fffu + ((u >> 16) & 1u);
  return (unsigned short)(u >> 16);
}

__device__ __forceinline__ void gl_lds16(const void* g, void* l) {
  __builtin_amdgcn_global_load_lds(
      (const __attribute__((address_space(1))) void*)g,
      (__attribute__((address_space(3))) void*)l, 16, 0, 0);
}

template <int NT>
__device__ __forceinline__ float block_reduce_sum(float v, float* red) {
  int t = threadIdx.x;
  __syncthreads();
  red[t] = v;
  __syncthreads();
#pragma unroll
  for (int s = NT / 2; s > 0; s >>= 1) {
    if (t < s) red[t] += red[t + s];
    __syncthreads();
  }
  return red[0];
}

// kA: fused proxy-normalize (blocks [0,K5_BLOCKS)) + X-normalize/Pb/diag.
// Zeroes k6's arrive counter (workspace is re-poisoned between iterations).
__global__ __launch_bounds__(256) void kA(const float* __restrict__ X,
                                          const float* __restrict__ proxies,
                                          const int* __restrict__ T,
                                          float* __restrict__ Xn, float* __restrict__ Pb,
                                          float* __restrict__ diagv,
                                          unsigned short* __restrict__ Pnb,
                                          int* __restrict__ ctrs) {
  int bid = blockIdx.x;
  int t = threadIdx.x;
  if (bid < K5_BLOCKS) {
    int lane = t & 63;
    int row = bid * 4 + (t >> 6);
    float2 v = make_float2(0.f, 0.f);
    if (row < C_N) v = *(const float2*)(proxies + (size_t)row * D_N + 2 * lane);
    float ss = v.x * v.x + v.y * v.y;
#pragma unroll
    for (int off = 1; off < 64; off <<= 1) ss += __shfl_xor(ss, off);
    float inv = 1.f / fmaxf(sqrtf(ss), 1e-12f);
    unsigned short a = f2bf(v.x * inv), b = f2bf(v.y * inv);
    unsigned int pk = (unsigned int)a | ((unsigned int)b << 16);
    *(unsigned int*)(Pnb + (size_t)row * D_N + 2 * lane) = pk;  // pad rows -> exact zeros
  } else {
    __shared__ float red[256];
    int b = bid - K5_BLOCKS;
    bool act = t < D_N;
    float v = act ? X[b * D_N + t] : 0.f;
    float ss = block_reduce_sum<256>(v * v, red);
    float xn = v / fmaxf(sqrtf(ss), 1e-12f);
    if (act) Xn[b * D_N + t] = xn;
    int row = T[b];
    float p = act ? proxies[(size_t)row * D_N + t] : 0.f;
    float ss2 = block_reduce_sum<256>(p * p, red);
    float pn = p / fmaxf(sqrtf(ss2), 1e-12f);
    if (act) Pb[b * D_N + t] = pn;
    float d = block_reduce_sum<256>(pn * xn, red);
    if (t == 0) {
      diagv[b] = d;
      if (b == 0) ctrs[32] = 0;  // k6 arrive counter, own cache line
    }
  }
}

// k3: A[b,k] = relu(0.5*(Pb[b].Xn[k]+diag[k])) + relu(Xn[b].Xn[k]); S[b]=row sum.
// 512 threads (1 k per thread): 16 waves/CU at grid 512 for latency hiding
// (the 256-thread/2-k version ran ~5% VALUBusy, latency-bound at 8 waves/CU).
__global__ __launch_bounds__(512) void k3_att(const float* __restrict__ Xn,
                                              const float* __restrict__ Pb,
                                              const float* __restrict__ diagv,
                                              float* __restrict__ A, float* __restrict__ S) {
  __shared__ float xb[128], pbv[128];
  __shared__ float red[512];
  int b = blockIdx.x, t = threadIdx.x;
  if (t < 128) {
    xb[t] = Xn[b * D_N + t];
    pbv[t] = Pb[b * D_N + t];
  }
  __syncthreads();
  const float4* xr = (const float4*)(Xn + (size_t)t * D_N);
  float d1 = 0.f, d2 = 0.f;
#pragma unroll
  for (int i = 0; i < 32; i++) {
    float4 v = xr[i];
    d1 += pbv[4 * i] * v.x + pbv[4 * i + 1] * v.y + pbv[4 * i + 2] * v.z + pbv[4 * i + 3] * v.w;
    d2 += xb[4 * i] * v.x + xb[4 * i + 1] * v.y + xb[4 * i + 2] * v.z + xb[4 * i + 3] * v.w;
  }
  float a = fmaxf(0.5f * (d1 + diagv[t]), 0.f) + fmaxf(d2, 0.f);
  A[(size_t)b * B_N + t] = a;
  float rs = block_reduce_sum<512>(a, red);
  if (t == 0) S[b] = rs;
}

// k4ab: fused k4a+k4b. Block b owns row b: aw[k]=A[b,k]/(S[k]+eps) in LDS,
// X2row = Xn[b,:] + aw @ Xn (no global X2 / no atomics), then renorm ->
// Xsb bf16, lossT[b], zero k6 sumexp state. The S dependency is carried by
// the k3->k4ab launch boundary (the spin grid-barrier cost 63us in R1:
// agent-scope polling of one line showed up as ~12MB FETCH / ~22MB WRITE).
__global__ __launch_bounds__(512) void k4ab(const float* __restrict__ Xn,
                                            const float* __restrict__ Pb,
                                            const float* __restrict__ A,
                                            const float* __restrict__ S,
                                            unsigned short* __restrict__ Xsb,
                                            float* __restrict__ lossT,
                                            float* __restrict__ sumexpP) {
  __shared__ float xb[128], pbv[128];
  __shared__ float aw[512];
  __shared__ float red[512];
  int b = blockIdx.x, t = threadIdx.x;
  if (t < 128) {
    xb[t] = Xn[b * D_N + t];
    pbv[t] = Pb[b * D_N + t];
  }
  aw[t] = A[(size_t)b * B_N + t] / (S[t] + 1e-5f);
  __syncthreads();

  // matvec: 4 k-quarters x 128 dims; 4 accumulators break the FMA dep chain
  int d = t & 127, h = t >> 7;
  const float* xp = Xn + (size_t)(128 * h) * D_N + d;
  const float* awp = aw + 128 * h;
  float a0 = 0.f, a1 = 0.f, a2 = 0.f, a3 = 0.f;
#pragma unroll 8
  for (int kk = 0; kk < 128; kk += 4) {
    a0 = fmaf(awp[kk], xp[(size_t)kk * D_N], a0);
    a1 = fmaf(awp[kk + 1], xp[(size_t)(kk + 1) * D_N], a1);
    a2 = fmaf(awp[kk + 2], xp[(size_t)(kk + 2) * D_N], a2);
    a3 = fmaf(awp[kk + 3], xp[(size_t)(kk + 3) * D_N], a3);
  }
  red[t] = (a0 + a1) + (a2 + a3);
  __syncthreads();
  float x2 = (t < 128) ? (xb[t] + red[t] + red[t + 128] + red[t + 256] + red[t + 384]) : 0.f;

  // renorm + epilogue (old k4b)
  float ss = block_reduce_sum<512>(x2 * x2, red);
  float xs = 3.f * x2 / fmaxf(sqrtf(ss), 1e-12f);
  if (t < 128) Xsb[b * D_N + t] = f2bf(xs);
  float dt = block_reduce_sum<512>((t < 128) ? xs * pbv[t] : 0.f, red);
  if (t == 0) {
    lossT[b] = fmaxf(18.f - 6.f * dt, 0.f);
    sumexpP[b * 16] = 0.f;
  }
}

// K6: Dm[b,c] = max(18 - 6*dot(Xs[b], Pn[c]), 0); sumexp[b] += sum_c exp(-Dm)
// grid (256,2), block 256, tile 256 b x 64 c (4 m-tiles/wave). Epilogue uses
// exp2 with log2e folded into the existing FMA (verified absmax-clean in R1).
__global__ __launch_bounds__(256, 2) void k6_big(const unsigned short* __restrict__ Pnb,
                                                 const unsigned short* __restrict__ Xsb,
                                                 float* __restrict__ sumexpP,
                                                 const float* __restrict__ lossT,
                                                 int* __restrict__ ctrs,
                                                 float* __restrict__ out) {
  __shared__ __align__(16) unsigned short sP[2][64 * 128];  // 2 x 16 KB, XOR-swizzled
  __shared__ float redf[256];
  __shared__ int sLast;
  const int t = threadIdx.x;
  const int w = t >> 6;
  const int lane = t & 63;
  const int lc = lane & 15;
  const int q = lane >> 4;
  const int b0 = blockIdx.y * 256;

  // A-fragments once from global bf16 Xsb: wave w owns m-rows 64w..64w+63
  short8 afr[4][4];
#pragma unroll
  for (int mt = 0; mt < 4; mt++)
#pragma unroll
    for (int ks = 0; ks < 4; ks++)
      afr[mt][ks] = *(const short8*)(Xsb + (size_t)(b0 + 64 * w + 16 * mt + lc) * D_N +
                                     ks * 32 + q * 8);

  float pe[4][4];
#pragma unroll
  for (int mt = 0; mt < 4; mt++)
#pragma unroll
    for (int r = 0; r < 4; r++) pe[mt][r] = 0.f;

  // staging: wave w stages rows 16w..16w+15 (4 instr x 1024 B); dest granule
  // (R,P) holds global granule g = P ^ (R&15) (bank swizzle, DMA-compatible).
  const int rR = 16 * w + (lane >> 4);
  const int gsrc0 = (lane & 15);
#define STAGE(c0_, buf_)                                                              \
  {                                                                                   \
    _Pragma("unroll") for (int j = 0; j < 4; j++) {                                   \
      int R = rR + 4 * j;                                                             \
      int g = gsrc0 ^ ((R)&15);                                                       \
      gl_lds16(Pnb + (((size_t)(c0_) + R) << 7) + (g << 3),                           \
               &sP[buf_][w * 2048 + j * 512]);                                        \
    }                                                                                 \
  }

  int cc = blockIdx.x;
  STAGE(cc * 64, 0);
  int buf = 0;
  while (true) {
    int nc = cc + gridDim.x;
    if (nc < NCHUNK) STAGE(nc * 64, buf ^ 1);  // issue next-buffer DMA early
    __builtin_amdgcn_sched_barrier(0);         // keep stage issue above the wait
    __builtin_amdgcn_s_waitcnt(0x0F74);        // vmcnt<=4: current buf landed, next in flight
    __builtin_amdgcn_s_barrier();              // rendezvous (NO vmcnt(0) drain)
    __builtin_amdgcn_sched_barrier(0);         // no ds_read hoist above barrier

    f32x4 acc[4][4];
#pragma unroll
    for (int mt = 0; mt < 4; mt++)
#pragma unroll
      for (int nt = 0; nt < 4; nt++) acc[mt][nt] = (f32x4){0.f, 0.f, 0.f, 0.f};

#pragma unroll
    for (int ks = 0; ks < 4; ks++) {
      short8 bfr[4];
#pragma unroll
      for (int nt = 0; nt < 4; nt++) {
        int R = 16 * nt + lc;
        int g = (ks * 4 + q) ^ lc;  // R&15 == lc
        bfr[nt] = *(const short8*)(&sP[buf][R * 128 + (g << 3)]);
      }
#pragma unroll
      for (int nt = 0; nt < 4; nt++)
#pragma unroll
        for (int mt = 0; mt < 4; mt++)
          acc[mt][nt] = __builtin_amdgcn_mfma_f32_16x16x32_bf16(afr[mt][ks], bfr[nt],
                                                                acc[mt][nt], 0, 0, 0);
    }

    // epilogue: no bounds predicate — pad rows are zero vectors, corrected at end.
    // exp(min(6a-18,0)) == exp2(min((6*log2e)a - 18*log2e, 0)) — log2e folded in FMA.
#pragma unroll
    for (int mt = 0; mt < 4; mt++)
#pragma unroll
      for (int nt = 0; nt < 4; nt++) {
        f32x4 a = acc[mt][nt];
#pragma unroll
        for (int r = 0; r < 4; r++)
          pe[mt][r] += __builtin_amdgcn_exp2f(
              fminf(__fmaf_rn(8.65617024533378f, a[r], -25.9685107360013f), 0.f));
      }

    if (nc >= NCHUNK) break;
    __builtin_amdgcn_sched_barrier(0);  // ds_reads stay above the release barrier
    __builtin_amdgcn_s_barrier();       // all waves done reading buf -> restage safe
    cc = nc;
    buf ^= 1;
  }

  // reduce over 16 col-lanes; one padded atomic per row
#pragma unroll
  for (int mt = 0; mt < 4; mt++) {
#pragma unroll
    for (int r = 0; r < 4; r++) {
      float p = pe[mt][r];
      p += __shfl_xor(p, 1);
      p += __shfl_xor(p, 2);
      p += __shfl_xor(p, 4);
      p += __shfl_xor(p, 8);
      if (lc == 0) {
        int rb = b0 + 64 * w + 16 * mt + 4 * q + r;
        atomicAdd(&sumexpP[rb * 16], p);
      }
    }
  }

  // fused k7: last block to arrive reduces the loss. Atomics complete at the
  // device coherence point; ordering needs only vmcnt(0) (NO threadfence --
  // agent fences emit L2 writeback/invalidate, measured ~46 us over the grid).
  __builtin_amdgcn_s_waitcnt(0);
  if (t == 0) sLast = atomicAdd(&ctrs[32], 1);
  __syncthreads();
  if (sLast == K6_BLOCKS - 1) {
    float v = 0.f;
#pragma unroll
    for (int i = 0; i < 2; i++) {
      int b = t + 256 * i;
      float se = __hip_atomic_load(&sumexpP[b * 16], __ATOMIC_RELAXED,
                                   __HIP_MEMORY_SCOPE_AGENT);
      v += lossT[b] + logf(se - PAD_CORR);
    }
    float s = block_reduce_sum<256>(v, redf);
    if (t == 0) out[0] = s * (1.0f / 512.0f);
  }
}

extern "C" void kernel_launch(void* const* d_in, const int* in_sizes, int n_in,
                              void* d_out, int out_size, void* d_ws, size_t ws_size,
                              hipStream_t stream) {
  const float* X = (const float*)d_in[0];
  const int* T = (const int*)d_in[2];
  const float* proxies = (const float*)d_in[3];
  float* out = (float*)d_out;

  char* ws = (char*)d_ws;
  unsigned short* Pnb = (unsigned short*)ws;               // CPAD*128 bf16 = 25.6 MB
  float* Xn = (float*)(ws + (size_t)CPAD * D_N * 2);       // 512*128
  float* Pb = Xn + B_N * D_N;                              // 512*128
  float* X2 = Pb + B_N * D_N;                              // 512*128 (unused, layout kept)
  float* dg = X2 + B_N * D_N;                              // 512
  float* S = dg + B_N;                                     // 512
  float* lossT = S + B_N;                                  // 512
  float* sumexpP = lossT + B_N;                            // 512*16 (line-padded)
  unsigned short* Xsb = (unsigned short*)(sumexpP + B_N * 16);  // 512*128 bf16
  float* A = (float*)(Xsb + B_N * D_N);                    // 512*512
  int* ctrs = (int*)(A + B_N * B_N);                       // [32] = k6 arrive counter

  kA<<<K5_BLOCKS + B_N, 256, 0, stream>>>(X, proxies, T, Xn, Pb, dg, Pnb, ctrs);
  k3_att<<<B_N, 512, 0, stream>>>(Xn, Pb, dg, A, S);
  k4ab<<<B_N, 512, 0, stream>>>(Xn, Pb, A, S, Xsb, lossT, sumexpP);
  k6_big<<<dim3(K6_GX, K6_GY), 256, 0, stream>>>(Pnb, Xsb, sumexpP, lossT, ctrs, out);
}

// Round 3
// 151.301 us; speedup vs baseline: 1.2324x; 1.0108x over previous
//
#include <hip/hip_runtime.h>
#include <hip/hip_bf16.h>
#include <math.h>

#define B_N 512
#define C_N 100000
#define CPAD 100032          // padded to multiple of 64
#define D_N 128
#define NCHUNK (CPAD / 64)   // 1563
#define KP_BLOCKS (CPAD / 8) // 12504: kA proxy blocks, 8 rows/block
#define K6_GX 256
#define K6_BLOCKS K6_GX
// each proxy pad row (zero vector) contributes exp(-18) to every row's sumexp
#define PAD_CORR (32.0f * 1.522998e-8f)

typedef short short8 __attribute__((ext_vector_type(8)));
typedef float f32x4 __attribute__((ext_vector_type(4)));

__device__ __forceinline__ unsigned short f2bf(float f) {
  unsigned int u = __float_as_uint(f);
  u += 0x7fffu + ((u >> 16) & 1u);
  return (unsigned short)(u >> 16);
}

__device__ __forceinline__ void gl_lds16(const void* g, void* l) {
  __builtin_amdgcn_global_load_lds(
      (const __attribute__((address_space(1))) void*)g,
      (__attribute__((address_space(3))) void*)l, 16, 0, 0);
}

template <int NT>
__device__ __forceinline__ float block_reduce_sum(float v, float* red) {
  int t = threadIdx.x;
  __syncthreads();
  red[t] = v;
  __syncthreads();
#pragma unroll
  for (int s = NT / 2; s > 0; s >>= 1) {
    if (t < s) red[t] += red[t + s];
    __syncthreads();
  }
  return red[0];
}

// kA: fused proxy-normalize (blocks [0,KP_BLOCKS)) + X-normalize/Pb/diag.
// Proxy pass re-tiled R3: 2 rows/wave, float4 loads (16B/lane), half-wave
// shfl reduce (5 steps, xor<32 stays in half), uint2 stores (8B/lane) —
// halves block count and per-byte instruction count vs float2/uint.
__global__ __launch_bounds__(256) void kA(const float* __restrict__ X,
                                          const float* __restrict__ proxies,
                                          const int* __restrict__ T,
                                          float* __restrict__ Xn, float* __restrict__ Pb,
                                          float* __restrict__ diagv,
                                          unsigned short* __restrict__ Pnb,
                                          int* __restrict__ ctrs) {
  int bid = blockIdx.x;
  int t = threadIdx.x;
  if (bid < KP_BLOCKS) {
    int w = t >> 6, lane = t & 63;
    int half = lane >> 5, l32 = lane & 31;
    int row = bid * 8 + w * 2 + half;
    float4 v = make_float4(0.f, 0.f, 0.f, 0.f);
    if (row < C_N) v = *(const float4*)(proxies + (size_t)row * D_N + 4 * l32);
    float ss = v.x * v.x + v.y * v.y + v.z * v.z + v.w * v.w;
#pragma unroll
    for (int off = 1; off < 32; off <<= 1) ss += __shfl_xor(ss, off);
    float inv = 1.f / fmaxf(sqrtf(ss), 1e-12f);
    unsigned int p0 = (unsigned int)f2bf(v.x * inv) | ((unsigned int)f2bf(v.y * inv) << 16);
    unsigned int p1 = (unsigned int)f2bf(v.z * inv) | ((unsigned int)f2bf(v.w * inv) << 16);
    *(uint2*)(Pnb + (size_t)row * D_N + 4 * l32) = make_uint2(p0, p1);  // pad rows -> zeros
  } else {
    __shared__ float red[256];
    int b = bid - KP_BLOCKS;
    bool act = t < D_N;
    float v = act ? X[b * D_N + t] : 0.f;
    float ss = block_reduce_sum<256>(v * v, red);
    float xn = v / fmaxf(sqrtf(ss), 1e-12f);
    if (act) Xn[b * D_N + t] = xn;
    int row = T[b];
    float p = act ? proxies[(size_t)row * D_N + t] : 0.f;
    float ss2 = block_reduce_sum<256>(p * p, red);
    float pn = p / fmaxf(sqrtf(ss2), 1e-12f);
    if (act) Pb[b * D_N + t] = pn;
    float d = block_reduce_sum<256>(pn * xn, red);
    if (t == 0) {
      diagv[b] = d;
      if (b == 0) ctrs[32] = 0;  // k6 arrive counter, own cache line
    }
  }
}

// k3: A[b,k] = relu(0.5*(Pb[b].Xn[k]+diag[k])) + relu(Xn[b].Xn[k]); S[b]=row sum.
__global__ __launch_bounds__(512) void k3_att(const float* __restrict__ Xn,
                                              const float* __restrict__ Pb,
                                              const float* __restrict__ diagv,
                                              float* __restrict__ A, float* __restrict__ S) {
  __shared__ float xb[128], pbv[128];
  __shared__ float red[512];
  int b = blockIdx.x, t = threadIdx.x;
  if (t < 128) {
    xb[t] = Xn[b * D_N + t];
    pbv[t] = Pb[b * D_N + t];
  }
  __syncthreads();
  const float4* xr = (const float4*)(Xn + (size_t)t * D_N);
  float d1 = 0.f, d2 = 0.f;
#pragma unroll
  for (int i = 0; i < 32; i++) {
    float4 v = xr[i];
    d1 += pbv[4 * i] * v.x + pbv[4 * i + 1] * v.y + pbv[4 * i + 2] * v.z + pbv[4 * i + 3] * v.w;
    d2 += xb[4 * i] * v.x + xb[4 * i + 1] * v.y + xb[4 * i + 2] * v.z + xb[4 * i + 3] * v.w;
  }
  float a = fmaxf(0.5f * (d1 + diagv[t]), 0.f) + fmaxf(d2, 0.f);
  A[(size_t)b * B_N + t] = a;
  float rs = block_reduce_sum<512>(a, red);
  if (t == 0) S[b] = rs;
}

// k4ab: fused k4a+k4b. Block b owns row b: aw[k]=A[b,k]/(S[k]+eps) in LDS,
// X2row = Xn[b,:] + aw @ Xn (no global X2 / no atomics), then renorm ->
// Xsb bf16, lossT[b], zero k6 sumexp state.
__global__ __launch_bounds__(512) void k4ab(const float* __restrict__ Xn,
                                            const float* __restrict__ Pb,
                                            const float* __restrict__ A,
                                            const float* __restrict__ S,
                                            unsigned short* __restrict__ Xsb,
                                            float* __restrict__ lossT,
                                            float* __restrict__ sumexpP) {
  __shared__ float xb[128], pbv[128];
  __shared__ float aw[512];
  __shared__ float red[512];
  int b = blockIdx.x, t = threadIdx.x;
  if (t < 128) {
    xb[t] = Xn[b * D_N + t];
    pbv[t] = Pb[b * D_N + t];
  }
  aw[t] = A[(size_t)b * B_N + t] / (S[t] + 1e-5f);
  __syncthreads();

  // matvec: 4 k-quarters x 128 dims; 4 accumulators break the FMA dep chain
  int d = t & 127, h = t >> 7;
  const float* xp = Xn + (size_t)(128 * h) * D_N + d;
  const float* awp = aw + 128 * h;
  float a0 = 0.f, a1 = 0.f, a2 = 0.f, a3 = 0.f;
#pragma unroll 8
  for (int kk = 0; kk < 128; kk += 4) {
    a0 = fmaf(awp[kk], xp[(size_t)kk * D_N], a0);
    a1 = fmaf(awp[kk + 1], xp[(size_t)(kk + 1) * D_N], a1);
    a2 = fmaf(awp[kk + 2], xp[(size_t)(kk + 2) * D_N], a2);
    a3 = fmaf(awp[kk + 3], xp[(size_t)(kk + 3) * D_N], a3);
  }
  red[t] = (a0 + a1) + (a2 + a3);
  __syncthreads();
  float x2 = (t < 128) ? (xb[t] + red[t] + red[t + 128] + red[t + 256] + red[t + 384]) : 0.f;

  // renorm + epilogue (old k4b)
  float ss = block_reduce_sum<512>(x2 * x2, red);
  float xs = 3.f * x2 / fmaxf(sqrtf(ss), 1e-12f);
  if (t < 128) Xsb[b * D_N + t] = f2bf(xs);
  float dt = block_reduce_sum<512>((t < 128) ? xs * pbv[t] : 0.f, red);
  if (t == 0) {
    lossT[b] = fmaxf(18.f - 6.f * dt, 0.f);
    sumexpP[b * 16] = 0.f;
  }
}

// K6: Dm[b,c] = max(18 - 6*dot(Xs[b], Pn[c]), 0); sumexp[b] += sum_c exp(-Dm)
// R3: grid 256 x 512 threads (8 waves, 1 block/CU, 2 waves/SIMD). The 8 waves
// cover all 512 b-rows, so each 16 KB Pnb chunk is staged ONCE (was twice via
// gy=2): chunk-visits 3126->1563, Pnb fetch 51.2->25.6 MB, per-visit sync
// overhead halved. Same XOR bank swizzle; 2 DMA instr/wave (vmcnt<=2); final
// iteration drains vmcnt(0) (fixes latent last-chunk race).
__global__ __launch_bounds__(512, 2) void k6_big(const unsigned short* __restrict__ Pnb,
                                                 const unsigned short* __restrict__ Xsb,
                                                 float* __restrict__ sumexpP,
                                                 const float* __restrict__ lossT,
                                                 int* __restrict__ ctrs,
                                                 float* __restrict__ out) {
  __shared__ __align__(16) unsigned short sP[2][64 * 128];  // 2 x 16 KB, XOR-swizzled
  __shared__ float redf[512];
  __shared__ int sLast;
  const int t = threadIdx.x;
  const int w = t >> 6;        // 0..7
  const int lane = t & 63;
  const int lc = lane & 15;
  const int q = lane >> 4;

  // A-fragments once from global bf16 Xsb: wave w owns m-rows 64w..64w+63
  short8 afr[4][4];
#pragma unroll
  for (int mt = 0; mt < 4; mt++)
#pragma unroll
    for (int ks = 0; ks < 4; ks++)
      afr[mt][ks] = *(const short8*)(Xsb + (size_t)(64 * w + 16 * mt + lc) * D_N +
                                     ks * 32 + q * 8);

  float pe[4][4];
#pragma unroll
  for (int mt = 0; mt < 4; mt++)
#pragma unroll
    for (int r = 0; r < 4; r++) pe[mt][r] = 0.f;

  // staging: wave w stages rows 8w..8w+7 (2 instr x 1024 B); dest granule
  // (R,P) holds global granule g = P ^ (R&15) (bank swizzle, DMA-compatible).
  const int rR = 8 * w + (lane >> 4);
  const int gsrc0 = (lane & 15);
#define STAGE(c0_, buf_)                                                              \
  {                                                                                   \
    _Pragma("unroll") for (int j = 0; j < 2; j++) {                                   \
      int R = rR + 4 * j;                                                             \
      int g = gsrc0 ^ ((R)&15);                                                       \
      gl_lds16(Pnb + (((size_t)(c0_) + R) << 7) + (g << 3),                           \
               &sP[buf_][w * 1024 + j * 512]);                                        \
    }                                                                                 \
  }

  int cc = blockIdx.x;
  STAGE(cc * 64, 0);
  int buf = 0;
  while (true) {
    int nc = cc + gridDim.x;
    if (nc < NCHUNK) {
      STAGE(nc * 64, buf ^ 1);             // issue next-buffer DMA early
      __builtin_amdgcn_sched_barrier(0);   // keep stage issue above the wait
      __builtin_amdgcn_s_waitcnt(0x0F72);  // vmcnt<=2: current buf landed, next in flight
    } else {
      __builtin_amdgcn_sched_barrier(0);
      __builtin_amdgcn_s_waitcnt(0x0F70);  // last chunk: drain (nothing else in flight)
    }
    __builtin_amdgcn_s_barrier();          // rendezvous (NO full drain in steady state)
    __builtin_amdgcn_sched_barrier(0);     // no ds_read hoist above barrier

    f32x4 acc[4][4];
#pragma unroll
    for (int mt = 0; mt < 4; mt++)
#pragma unroll
      for (int nt = 0; nt < 4; nt++) acc[mt][nt] = (f32x4){0.f, 0.f, 0.f, 0.f};

#pragma unroll
    for (int ks = 0; ks < 4; ks++) {
      short8 bfr[4];
#pragma unroll
      for (int nt = 0; nt < 4; nt++) {
        int R = 16 * nt + lc;
        int g = (ks * 4 + q) ^ lc;  // R&15 == lc
        bfr[nt] = *(const short8*)(&sP[buf][R * 128 + (g << 3)]);
      }
#pragma unroll
      for (int nt = 0; nt < 4; nt++)
#pragma unroll
        for (int mt = 0; mt < 4; mt++)
          acc[mt][nt] = __builtin_amdgcn_mfma_f32_16x16x32_bf16(afr[mt][ks], bfr[nt],
                                                                acc[mt][nt], 0, 0, 0);
    }

    // epilogue: no bounds predicate — pad rows are zero vectors, corrected at end.
    // exp(min(6a-18,0)) == exp2(min((6*log2e)a - 18*log2e, 0)) — log2e folded in FMA.
#pragma unroll
    for (int mt = 0; mt < 4; mt++)
#pragma unroll
      for (int nt = 0; nt < 4; nt++) {
        f32x4 a = acc[mt][nt];
#pragma unroll
        for (int r = 0; r < 4; r++)
          pe[mt][r] += __builtin_amdgcn_exp2f(
              fminf(__fmaf_rn(8.65617024533378f, a[r], -25.9685107360013f), 0.f));
      }

    if (nc >= NCHUNK) break;
    __builtin_amdgcn_sched_barrier(0);  // ds_reads stay above the release barrier
    __builtin_amdgcn_s_barrier();       // all waves done reading buf -> restage safe
    cc = nc;
    buf ^= 1;
  }

  // reduce over 16 col-lanes; one padded atomic per row
#pragma unroll
  for (int mt = 0; mt < 4; mt++) {
#pragma unroll
    for (int r = 0; r < 4; r++) {
      float p = pe[mt][r];
      p += __shfl_xor(p, 1);
      p += __shfl_xor(p, 2);
      p += __shfl_xor(p, 4);
      p += __shfl_xor(p, 8);
      if (lc == 0) {
        int rb = 64 * w + 16 * mt + 4 * q + r;
        atomicAdd(&sumexpP[rb * 16], p);
      }
    }
  }

  // fused k7: last block to arrive reduces the loss. Atomics complete at the
  // device coherence point; ordering needs only vmcnt(0) (NO threadfence --
  // agent fences emit L2 writeback/invalidate, measured ~46 us over the grid).
  __builtin_amdgcn_s_waitcnt(0);
  if (t == 0) sLast = atomicAdd(&ctrs[32], 1);
  __syncthreads();
  if (sLast == K6_BLOCKS - 1) {
    float se = __hip_atomic_load(&sumexpP[t * 16], __ATOMIC_RELAXED,
                                 __HIP_MEMORY_SCOPE_AGENT);
    float v = lossT[t] + logf(se - PAD_CORR);
    float s = block_reduce_sum<512>(v, redf);
    if (t == 0) out[0] = s * (1.0f / 512.0f);
  }
}

extern "C" void kernel_launch(void* const* d_in, const int* in_sizes, int n_in,
                              void* d_out, int out_size, void* d_ws, size_t ws_size,
                              hipStream_t stream) {
  const float* X = (const float*)d_in[0];
  const int* T = (const int*)d_in[2];
  const float* proxies = (const float*)d_in[3];
  float* out = (float*)d_out;

  char* ws = (char*)d_ws;
  unsigned short* Pnb = (unsigned short*)ws;               // CPAD*128 bf16 = 25.6 MB
  float* Xn = (float*)(ws + (size_t)CPAD * D_N * 2);       // 512*128
  float* Pb = Xn + B_N * D_N;                              // 512*128
  float* X2 = Pb + B_N * D_N;                              // 512*128 (unused, layout kept)
  float* dg = X2 + B_N * D_N;                              // 512
  float* S = dg + B_N;                                     // 512
  float* lossT = S + B_N;                                  // 512
  float* sumexpP = lossT + B_N;                            // 512*16 (line-padded)
  unsigned short* Xsb = (unsigned short*)(sumexpP + B_N * 16);  // 512*128 bf16
  float* A = (float*)(Xsb + B_N * D_N);                    // 512*512
  int* ctrs = (int*)(A + B_N * B_N);                       // [32] = k6 arrive counter

  kA<<<KP_BLOCKS + B_N, 256, 0, stream>>>(X, proxies, T, Xn, Pb, dg, Pnb, ctrs);
  k3_att<<<B_N, 512, 0, stream>>>(Xn, Pb, dg, A, S);
  k4ab<<<B_N, 512, 0, stream>>>(Xn, Pb, A, S, Xsb, lossT, sumexpP);
  k6_big<<<K6_GX, 512, 0, stream>>>(Pnb, Xsb, sumexpP, lossT, ctrs, out);
}

// Round 4
// 142.260 us; speedup vs baseline: 1.3107x; 1.0635x over previous
//
#include <hip/hip_runtime.h>
#include <hip/hip_bf16.h>
#include <math.h>

#define B_N 512
#define C_N 100000
#define CPAD 100032          // padded to multiple of 64
#define D_N 128
#define NCHUNK (CPAD / 64)   // 1563
#define K6_GX 256
#define K6_BLOCKS K6_GX
// each proxy pad row (zero vector) contributes exp(-18) to every row's sumexp
#define PAD_CORR (32.0f * 1.522998e-8f)

typedef short short8 __attribute__((ext_vector_type(8)));
typedef float f32x4 __attribute__((ext_vector_type(4)));

__device__ __forceinline__ unsigned short f2bf(float f) {
  unsigned int u = __float_as_uint(f);
  u += 0x7fffu + ((u >> 16) & 1u);
  return (unsigned short)(u >> 16);
}

__device__ __forceinline__ unsigned int pk2bf(float lo, float hi) {
  return (unsigned int)f2bf(lo) | ((unsigned int)f2bf(hi) << 16);
}

__device__ __forceinline__ void gl_lds16(const void* g, void* l) {
  __builtin_amdgcn_global_load_lds(
      (const __attribute__((address_space(1))) void*)g,
      (__attribute__((address_space(3))) void*)l, 16, 0, 0);
}

template <int NT>
__device__ __forceinline__ float block_reduce_sum(float v, float* red) {
  int t = threadIdx.x;
  __syncthreads();
  red[t] = v;
  __syncthreads();
#pragma unroll
  for (int s = NT / 2; s > 0; s >>= 1) {
    if (t < s) red[t] += red[t + s];
    __syncthreads();
  }
  return red[0];
}

// kX: X-normalize + Pb gather-normalize + diag. The 77 MB proxy-normalize
// pass that used to live here is folded into k6 (each Pnb chunk was already
// staged by exactly one block exactly once, so the convert is block-local).
__global__ __launch_bounds__(256) void kX(const float* __restrict__ X,
                                          const float* __restrict__ proxies,
                                          const int* __restrict__ T,
                                          float* __restrict__ Xn, float* __restrict__ Pb,
                                          float* __restrict__ diagv,
                                          int* __restrict__ ctrs) {
  __shared__ float red[256];
  int b = blockIdx.x;
  int t = threadIdx.x;
  bool act = t < D_N;
  float v = act ? X[b * D_N + t] : 0.f;
  float ss = block_reduce_sum<256>(v * v, red);
  float xn = v / fmaxf(sqrtf(ss), 1e-12f);
  if (act) Xn[b * D_N + t] = xn;
  int row = T[b];
  float p = act ? proxies[(size_t)row * D_N + t] : 0.f;
  float ss2 = block_reduce_sum<256>(p * p, red);
  float pn = p / fmaxf(sqrtf(ss2), 1e-12f);
  if (act) Pb[b * D_N + t] = pn;
  float d = block_reduce_sum<256>(pn * xn, red);
  if (t == 0) {
    diagv[b] = d;
    if (b == 0) ctrs[32] = 0;  // k6 arrive counter, own cache line
  }
}

// k3: A[b,k] = relu(0.5*(Pb[b].Xn[k]+diag[k])) + relu(Xn[b].Xn[k]); S[b]=row sum.
__global__ __launch_bounds__(512) void k3_att(const float* __restrict__ Xn,
                                              const float* __restrict__ Pb,
                                              const float* __restrict__ diagv,
                                              float* __restrict__ A, float* __restrict__ S) {
  __shared__ float xb[128], pbv[128];
  __shared__ float red[512];
  int b = blockIdx.x, t = threadIdx.x;
  if (t < 128) {
    xb[t] = Xn[b * D_N + t];
    pbv[t] = Pb[b * D_N + t];
  }
  __syncthreads();
  const float4* xr = (const float4*)(Xn + (size_t)t * D_N);
  float d1 = 0.f, d2 = 0.f;
#pragma unroll
  for (int i = 0; i < 32; i++) {
    float4 v = xr[i];
    d1 += pbv[4 * i] * v.x + pbv[4 * i + 1] * v.y + pbv[4 * i + 2] * v.z + pbv[4 * i + 3] * v.w;
    d2 += xb[4 * i] * v.x + xb[4 * i + 1] * v.y + xb[4 * i + 2] * v.z + xb[4 * i + 3] * v.w;
  }
  float a = fmaxf(0.5f * (d1 + diagv[t]), 0.f) + fmaxf(d2, 0.f);
  A[(size_t)b * B_N + t] = a;
  float rs = block_reduce_sum<512>(a, red);
  if (t == 0) S[b] = rs;
}

// k4ab: fused k4a+k4b. Block b owns row b: aw[k]=A[b,k]/(S[k]+eps) in LDS,
// X2row = Xn[b,:] + aw @ Xn (no global X2 / no atomics), then renorm ->
// Xsb bf16, lossT[b], zero k6 sumexp state.
__global__ __launch_bounds__(512) void k4ab(const float* __restrict__ Xn,
                                            const float* __restrict__ Pb,
                                            const float* __restrict__ A,
                                            const float* __restrict__ S,
                                            unsigned short* __restrict__ Xsb,
                                            float* __restrict__ lossT,
                                            float* __restrict__ sumexpP) {
  __shared__ float xb[128], pbv[128];
  __shared__ float aw[512];
  __shared__ float red[512];
  int b = blockIdx.x, t = threadIdx.x;
  if (t < 128) {
    xb[t] = Xn[b * D_N + t];
    pbv[t] = Pb[b * D_N + t];
  }
  aw[t] = A[(size_t)b * B_N + t] / (S[t] + 1e-5f);
  __syncthreads();

  // matvec: 4 k-quarters x 128 dims; 4 accumulators break the FMA dep chain
  int d = t & 127, h = t >> 7;
  const float* xp = Xn + (size_t)(128 * h) * D_N + d;
  const float* awp = aw + 128 * h;
  float a0 = 0.f, a1 = 0.f, a2 = 0.f, a3 = 0.f;
#pragma unroll 8
  for (int kk = 0; kk < 128; kk += 4) {
    a0 = fmaf(awp[kk], xp[(size_t)kk * D_N], a0);
    a1 = fmaf(awp[kk + 1], xp[(size_t)(kk + 1) * D_N], a1);
    a2 = fmaf(awp[kk + 2], xp[(size_t)(kk + 2) * D_N], a2);
    a3 = fmaf(awp[kk + 3], xp[(size_t)(kk + 3) * D_N], a3);
  }
  red[t] = (a0 + a1) + (a2 + a3);
  __syncthreads();
  float x2 = (t < 128) ? (xb[t] + red[t] + red[t + 128] + red[t + 256] + red[t + 384]) : 0.f;

  // renorm + epilogue (old k4b)
  float ss = block_reduce_sum<512>(x2 * x2, red);
  float xs = 3.f * x2 / fmaxf(sqrtf(ss), 1e-12f);
  if (t < 128) Xsb[b * D_N + t] = f2bf(xs);
  float dt = block_reduce_sum<512>((t < 128) ? xs * pbv[t] : 0.f, red);
  if (t == 0) {
    lossT[b] = fmaxf(18.f - 6.f * dt, 0.f);
    sumexpP[b * 16] = 0.f;
  }
}

// K6: Dm[b,c] = max(18 - 6*dot(Xs[b], Pn[c]), 0); sumexp[b] += sum_c exp(-Dm).
// R4: stages RAW f32 proxies (2x32KB dbuf DMA) and normalizes+converts to the
// XOR-swizzled bf16 tile INSIDE the loop. Key alignment: each wave DMA-stages
// exactly the 8 rows it converts, so the convert pass is wave-local (no extra
// barrier). Sum-of-squares uses the same balanced tree as the old kA
// (4-quad per float4, then pairwise) -> bit-identical bf16 values. Pad rows
// (>=C_N) are clamp-sourced and predicate-zeroed (PAD_CORR unchanged).
// Eliminates the 77 MB kA proxy pass + the 25.6 MB Pnb re-read entirely.
__global__ __launch_bounds__(512, 2) void k6_big(const float* __restrict__ proxies,
                                                 const unsigned short* __restrict__ Xsb,
                                                 float* __restrict__ sumexpP,
                                                 const float* __restrict__ lossT,
                                                 int* __restrict__ ctrs,
                                                 float* __restrict__ out) {
  __shared__ __align__(16) float fP[2][64 * 128];        // 2 x 32 KB raw f32 staging
  __shared__ __align__(16) unsigned short sP[64 * 128];  // 16 KB bf16, XOR-swizzled
  __shared__ float redf[512];
  __shared__ int sLast;
  const int t = threadIdx.x;
  const int w = t >> 6;        // 0..7
  const int lane = t & 63;
  const int lc = lane & 15;
  const int q = lane >> 4;

  // A-fragments once from global bf16 Xsb: wave w owns m-rows 64w..64w+63
  short8 afr[4][4];
#pragma unroll
  for (int mt = 0; mt < 4; mt++)
#pragma unroll
    for (int ks = 0; ks < 4; ks++)
      afr[mt][ks] = *(const short8*)(Xsb + (size_t)(64 * w + 16 * mt + lc) * D_N +
                                     ks * 32 + q * 8);

  float pe[4][4];
#pragma unroll
  for (int mt = 0; mt < 4; mt++)
#pragma unroll
    for (int r = 0; r < 4; r++) pe[mt][r] = 0.f;

  // f32 staging: wave w stages rows 8w..8w+7 linearly (4 instr x 1024 B =
  // 2 rows each). Per lane: row += lane>>5, 16B granule at col (lane&31)*4.
  const int srow = 8 * w + (lane >> 5);
  const int scol = (lane & 31) * 4;
#define STAGEF(c0_, buf_)                                                             \
  {                                                                                   \
    _Pragma("unroll") for (int j = 0; j < 4; j++) {                                   \
      int gr = (c0_) + srow + 2 * j;                                                  \
      gr = gr < C_N ? gr : (C_N - 1); /* clamp pad rows: no OOB fault */              \
      gl_lds16(proxies + (size_t)gr * D_N + scol,                                     \
               &fP[buf_][(8 * w + 2 * j) * D_N]);                                     \
    }                                                                                 \
  }

  // convert-pass geometry: thread handles row cr=t>>3, cols 16*cs..16*cs+15
  const int cr = t >> 3;
  const int cs = t & 7;

  int cc = blockIdx.x;
  STAGEF(cc * 64, 0);
  int buf = 0;
  while (true) {
    int nc = cc + gridDim.x;
    if (nc < NCHUNK) {
      STAGEF(nc * 64, buf ^ 1);            // issue next-buffer DMA early
      __builtin_amdgcn_sched_barrier(0);   // keep stage issue above the wait
      __builtin_amdgcn_s_waitcnt(0x0F74);  // vmcnt<=4: current buf landed, next in flight
    } else {
      __builtin_amdgcn_sched_barrier(0);
      __builtin_amdgcn_s_waitcnt(0x0F70);  // last chunk: drain (nothing else in flight)
    }
    __builtin_amdgcn_sched_barrier(0);

    // ---- wave-local normalize + bf16 convert into swizzled sP ----
    // (fP rows 8w..8w+7 were staged by THIS wave; sP was released by the
    //  previous iteration's trailing barrier.)
    {
      const float* src = &fP[buf][cr * D_N + cs * 16];
      float4 v0 = ((const float4*)src)[0];
      float4 v1 = ((const float4*)src)[1];
      float4 v2 = ((const float4*)src)[2];
      float4 v3 = ((const float4*)src)[3];
      float s0 = v0.x * v0.x + v0.y * v0.y + v0.z * v0.z + v0.w * v0.w;
      float s1 = v1.x * v1.x + v1.y * v1.y + v1.z * v1.z + v1.w * v1.w;
      float s2 = v2.x * v2.x + v2.y * v2.y + v2.z * v2.z + v2.w * v2.w;
      float s3 = v3.x * v3.x + v3.y * v3.y + v3.z * v3.z + v3.w * v3.w;
      float ss = (s0 + s1) + (s2 + s3);  // balanced tree: matches old kA bit-exactly
      ss += __shfl_xor(ss, 1);
      ss += __shfl_xor(ss, 2);
      ss += __shfl_xor(ss, 4);
      float inv = 1.f / fmaxf(sqrtf(ss), 1e-12f);
      if (cc * 64 + cr >= C_N) inv = 0.f;  // pad rows -> exact zero vectors
      uint4 g0, g1;
      g0.x = pk2bf(v0.x * inv, v0.y * inv);
      g0.y = pk2bf(v0.z * inv, v0.w * inv);
      g0.z = pk2bf(v1.x * inv, v1.y * inv);
      g0.w = pk2bf(v1.z * inv, v1.w * inv);
      g1.x = pk2bf(v2.x * inv, v2.y * inv);
      g1.y = pk2bf(v2.z * inv, v2.w * inv);
      g1.z = pk2bf(v3.x * inv, v3.y * inv);
      g1.w = pk2bf(v3.z * inv, v3.w * inv);
      int P0 = (2 * cs) ^ (cr & 15);      // bank swizzle: phys granule = logical ^ (row&15)
      int P1 = (2 * cs + 1) ^ (cr & 15);
      *(uint4*)&sP[cr * D_N + P0 * 8] = g0;
      *(uint4*)&sP[cr * D_N + P1 * 8] = g1;
    }
    __builtin_amdgcn_s_waitcnt(0xC07F);  // lgkmcnt(0): own ds_writes done (NOT vmcnt)
    __builtin_amdgcn_s_barrier();        // sP tile ready for all waves
    __builtin_amdgcn_sched_barrier(0);   // no ds_read hoist above barrier

    f32x4 acc[4][4];
#pragma unroll
    for (int mt = 0; mt < 4; mt++)
#pragma unroll
      for (int nt = 0; nt < 4; nt++) acc[mt][nt] = (f32x4){0.f, 0.f, 0.f, 0.f};

#pragma unroll
    for (int ks = 0; ks < 4; ks++) {
      short8 bfr[4];
#pragma unroll
      for (int nt = 0; nt < 4; nt++) {
        int R = 16 * nt + lc;
        int g = (ks * 4 + q) ^ lc;  // R&15 == lc
        bfr[nt] = *(const short8*)(&sP[R * 128 + (g << 3)]);
      }
#pragma unroll
      for (int nt = 0; nt < 4; nt++)
#pragma unroll
        for (int mt = 0; mt < 4; mt++)
          acc[mt][nt] = __builtin_amdgcn_mfma_f32_16x16x32_bf16(afr[mt][ks], bfr[nt],
                                                                acc[mt][nt], 0, 0, 0);
    }

    // epilogue: pad cols are zero vectors -> exp(-18), corrected at the end.
    // exp(min(6a-18,0)) == exp2(min((6*log2e)a - 18*log2e, 0)), log2e in FMA.
#pragma unroll
    for (int mt = 0; mt < 4; mt++)
#pragma unroll
      for (int nt = 0; nt < 4; nt++) {
        f32x4 a = acc[mt][nt];
#pragma unroll
        for (int r = 0; r < 4; r++)
          pe[mt][r] += __builtin_amdgcn_exp2f(
              fminf(__fmaf_rn(8.65617024533378f, a[r], -25.9685107360013f), 0.f));
      }

    if (nc >= NCHUNK) break;
    __builtin_amdgcn_sched_barrier(0);  // ds_reads stay above the release barrier
    __builtin_amdgcn_s_barrier();       // all waves done reading sP -> next convert safe
    cc = nc;
    buf ^= 1;
  }

  // reduce over 16 col-lanes; one padded atomic per row
#pragma unroll
  for (int mt = 0; mt < 4; mt++) {
#pragma unroll
    for (int r = 0; r < 4; r++) {
      float p = pe[mt][r];
      p += __shfl_xor(p, 1);
      p += __shfl_xor(p, 2);
      p += __shfl_xor(p, 4);
      p += __shfl_xor(p, 8);
      if (lc == 0) {
        int rb = 64 * w + 16 * mt + 4 * q + r;
        atomicAdd(&sumexpP[rb * 16], p);
      }
    }
  }

  // fused k7: last block to arrive reduces the loss. Atomics complete at the
  // device coherence point; ordering needs only vmcnt(0) (NO threadfence --
  // agent fences emit L2 writeback/invalidate, measured ~46 us over the grid).
  __builtin_amdgcn_s_waitcnt(0);
  if (t == 0) sLast = atomicAdd(&ctrs[32], 1);
  __syncthreads();
  if (sLast == K6_BLOCKS - 1) {
    float se = __hip_atomic_load(&sumexpP[t * 16], __ATOMIC_RELAXED,
                                 __HIP_MEMORY_SCOPE_AGENT);
    float v = lossT[t] + logf(se - PAD_CORR);
    float s = block_reduce_sum<512>(v, redf);
    if (t == 0) out[0] = s * (1.0f / 512.0f);
  }
}

extern "C" void kernel_launch(void* const* d_in, const int* in_sizes, int n_in,
                              void* d_out, int out_size, void* d_ws, size_t ws_size,
                              hipStream_t stream) {
  const float* X = (const float*)d_in[0];
  const int* T = (const int*)d_in[2];
  const float* proxies = (const float*)d_in[3];
  float* out = (float*)d_out;

  char* ws = (char*)d_ws;
  // (Pnb region retired -- offsets kept identical for layout stability)
  float* Xn = (float*)(ws + (size_t)CPAD * D_N * 2);       // 512*128
  float* Pb = Xn + B_N * D_N;                              // 512*128
  float* X2 = Pb + B_N * D_N;                              // 512*128 (unused, layout kept)
  float* dg = X2 + B_N * D_N;                              // 512
  float* S = dg + B_N;                                     // 512
  float* lossT = S + B_N;                                  // 512
  float* sumexpP = lossT + B_N;                            // 512*16 (line-padded)
  unsigned short* Xsb = (unsigned short*)(sumexpP + B_N * 16);  // 512*128 bf16
  float* A = (float*)(Xsb + B_N * D_N);                    // 512*512
  int* ctrs = (int*)(A + B_N * B_N);                       // [32] = k6 arrive counter

  kX<<<B_N, 256, 0, stream>>>(X, proxies, T, Xn, Pb, dg, ctrs);
  k3_att<<<B_N, 512, 0, stream>>>(Xn, Pb, dg, A, S);
  k4ab<<<B_N, 512, 0, stream>>>(Xn, Pb, A, S, Xsb, lossT, sumexpP);
  k6_big<<<K6_GX, 512, 0, stream>>>(proxies, Xsb, sumexpP, lossT, ctrs, out);
}

// Round 6
// 141.765 us; speedup vs baseline: 1.3153x; 1.0035x over previous
//
#include <hip/hip_runtime.h>
#include <hip/hip_bf16.h>
#include <math.h>

#define B_N 512
#define C_N 100000
#define CPAD 100032          // padded to multiple of 64
#define D_N 128
#define NCHUNK (CPAD / 64)   // 1563 = 256*6 + 27
#define K6_GX 256
#define K6_BLOCKS K6_GX
// each proxy pad row (zero vector) contributes exp(-18) to every row's sumexp
#define PAD_CORR (32.0f * 1.522998e-8f)

typedef short short8 __attribute__((ext_vector_type(8)));
typedef float f32x4 __attribute__((ext_vector_type(4)));

__device__ __forceinline__ unsigned short f2bf(float f) {
  unsigned int u = __float_as_uint(f);
  u += 0x7fffu + ((u >> 16) & 1u);
  return (unsigned short)(u >> 16);
}

__device__ __forceinline__ unsigned int pk2bf(float lo, float hi) {
  return (unsigned int)f2bf(lo) | ((unsigned int)f2bf(hi) << 16);
}

__device__ __forceinline__ void gl_lds16(const void* g, void* l) {
  __builtin_amdgcn_global_load_lds(
      (const __attribute__((address_space(1))) void*)g,
      (__attribute__((address_space(3))) void*)l, 16, 0, 0);
}

template <int NT>
__device__ __forceinline__ float block_reduce_sum(float v, float* red) {
  int t = threadIdx.x;
  __syncthreads();
  red[t] = v;
  __syncthreads();
#pragma unroll
  for (int s = NT / 2; s > 0; s >>= 1) {
    if (t < s) red[t] += red[t + s];
    __syncthreads();
  }
  return red[0];
}

// kX: X-normalize + Pb gather-normalize + diag. 128 threads (was 256 with
// half the lanes idle through three block reductions).
__global__ __launch_bounds__(128) void kX(const float* __restrict__ X,
                                          const float* __restrict__ proxies,
                                          const int* __restrict__ T,
                                          float* __restrict__ Xn, float* __restrict__ Pb,
                                          float* __restrict__ diagv,
                                          int* __restrict__ ctrs) {
  __shared__ float red[128];
  int b = blockIdx.x;
  int t = threadIdx.x;
  float v = X[b * D_N + t];
  float ss = block_reduce_sum<128>(v * v, red);
  float xn = v / fmaxf(sqrtf(ss), 1e-12f);
  Xn[b * D_N + t] = xn;
  int row = T[b];
  float p = proxies[(size_t)row * D_N + t];
  float ss2 = block_reduce_sum<128>(p * p, red);
  float pn = p / fmaxf(sqrtf(ss2), 1e-12f);
  Pb[b * D_N + t] = pn;
  float d = block_reduce_sum<128>(pn * xn, red);
  if (t == 0) {
    diagv[b] = d;
    if (b == 0) ctrs[32] = 0;  // k6 arrive counter, own cache line
  }
}

// k3: A[b,k] = relu(0.5*(Pb[b].Xn[k]+diag[k])) + relu(Xn[b].Xn[k]); S[b]=row sum.
__global__ __launch_bounds__(512) void k3_att(const float* __restrict__ Xn,
                                              const float* __restrict__ Pb,
                                              const float* __restrict__ diagv,
                                              float* __restrict__ A, float* __restrict__ S) {
  __shared__ float xb[128], pbv[128];
  __shared__ float red[512];
  int b = blockIdx.x, t = threadIdx.x;
  if (t < 128) {
    xb[t] = Xn[b * D_N + t];
    pbv[t] = Pb[b * D_N + t];
  }
  __syncthreads();
  const float4* xr = (const float4*)(Xn + (size_t)t * D_N);
  float d1 = 0.f, d2 = 0.f;
#pragma unroll
  for (int i = 0; i < 32; i++) {
    float4 v = xr[i];
    d1 += pbv[4 * i] * v.x + pbv[4 * i + 1] * v.y + pbv[4 * i + 2] * v.z + pbv[4 * i + 3] * v.w;
    d2 += xb[4 * i] * v.x + xb[4 * i + 1] * v.y + xb[4 * i + 2] * v.z + xb[4 * i + 3] * v.w;
  }
  float a = fmaxf(0.5f * (d1 + diagv[t]), 0.f) + fmaxf(d2, 0.f);
  A[(size_t)b * B_N + t] = a;
  float rs = block_reduce_sum<512>(a, red);
  if (t == 0) S[b] = rs;
}

// k4ab: fused k4a+k4b. Block b owns row b: aw[k]=A[b,k]/(S[k]+eps) in LDS,
// X2row = Xn[b,:] + aw @ Xn (no global X2 / no atomics), then renorm ->
// Xsb bf16, lossT[b], zero k6 sumexp state.
__global__ __launch_bounds__(512) void k4ab(const float* __restrict__ Xn,
                                            const float* __restrict__ Pb,
                                            const float* __restrict__ A,
                                            const float* __restrict__ S,
                                            unsigned short* __restrict__ Xsb,
                                            float* __restrict__ lossT,
                                            float* __restrict__ sumexpP) {
  __shared__ float xb[128], pbv[128];
  __shared__ float aw[512];
  __shared__ float red[512];
  int b = blockIdx.x, t = threadIdx.x;
  if (t < 128) {
    xb[t] = Xn[b * D_N + t];
    pbv[t] = Pb[b * D_N + t];
  }
  aw[t] = A[(size_t)b * B_N + t] / (S[t] + 1e-5f);
  __syncthreads();

  // matvec: 4 k-quarters x 128 dims; 4 accumulators break the FMA dep chain
  int d = t & 127, h = t >> 7;
  const float* xp = Xn + (size_t)(128 * h) * D_N + d;
  const float* awp = aw + 128 * h;
  float a0 = 0.f, a1 = 0.f, a2 = 0.f, a3 = 0.f;
#pragma unroll 8
  for (int kk = 0; kk < 128; kk += 4) {
    a0 = fmaf(awp[kk], xp[(size_t)kk * D_N], a0);
    a1 = fmaf(awp[kk + 1], xp[(size_t)(kk + 1) * D_N], a1);
    a2 = fmaf(awp[kk + 2], xp[(size_t)(kk + 2) * D_N], a2);
    a3 = fmaf(awp[kk + 3], xp[(size_t)(kk + 3) * D_N], a3);
  }
  red[t] = (a0 + a1) + (a2 + a3);
  __syncthreads();
  float x2 = (t < 128) ? (xb[t] + red[t] + red[t + 128] + red[t + 256] + red[t + 384]) : 0.f;

  // renorm + epilogue (old k4b)
  float ss = block_reduce_sum<512>(x2 * x2, red);
  float xs = 3.f * x2 / fmaxf(sqrtf(ss), 1e-12f);
  if (t < 128) Xsb[b * D_N + t] = f2bf(xs);
  float dt = block_reduce_sum<512>((t < 128) ? xs * pbv[t] : 0.f, red);
  if (t == 0) {
    lossT[b] = fmaxf(18.f - 6.f * dt, 0.f);
    sumexpP[b * 16] = 0.f;
  }
}

// K6: Dm[b,c] = max(18 - 6*dot(Xs[b], Pn[c]), 0); sumexp[b] += sum_c exp(-Dm).
// R5 (resubmit): (a) sP double-buffered -> ONE barrier per chunk (release
// barrier gone; safety: each wave's lgkmcnt(0) before the rendezvous drains
// its prior-iter sP reads, so writes 2 iters later can't race); (b) per-nt
// pipeline (4 ds_read -> 16 MFMA -> 16 exp) so exp VALU overlaps next nt's
// MFMAs and live acc shrinks 64->16 VGPR; (c) contiguous chunk ranges per
// block (block i owns chunks [6i+min(i,27) ...)) for sequential HBM streaming.
__global__ __launch_bounds__(512, 2) void k6_big(const float* __restrict__ proxies,
                                                 const unsigned short* __restrict__ Xsb,
                                                 float* __restrict__ sumexpP,
                                                 const float* __restrict__ lossT,
                                                 int* __restrict__ ctrs,
                                                 float* __restrict__ out) {
  __shared__ __align__(16) float fP[2][64 * 128];           // 2 x 32 KB raw f32 staging
  __shared__ __align__(16) unsigned short sP[2][64 * 128];  // 2 x 16 KB bf16, swizzled
  __shared__ float redf[512];
  __shared__ int sLast;
  const int t = threadIdx.x;
  const int w = t >> 6;        // 0..7
  const int lane = t & 63;
  const int lc = lane & 15;
  const int q = lane >> 4;

  // A-fragments once from global bf16 Xsb: wave w owns m-rows 64w..64w+63
  short8 afr[4][4];
#pragma unroll
  for (int mt = 0; mt < 4; mt++)
#pragma unroll
    for (int ks = 0; ks < 4; ks++)
      afr[mt][ks] = *(const short8*)(Xsb + (size_t)(64 * w + 16 * mt + lc) * D_N +
                                     ks * 32 + q * 8);

  float pe[4][4];
#pragma unroll
  for (int mt = 0; mt < 4; mt++)
#pragma unroll
    for (int r = 0; r < 4; r++) pe[mt][r] = 0.f;

  // f32 staging: wave w stages rows 8w..8w+7 linearly (4 instr x 1024 B =
  // 2 rows each). Per lane: row += lane>>5, 16B granule at col (lane&31)*4.
  const int srow = 8 * w + (lane >> 5);
  const int scol = (lane & 31) * 4;
#define STAGEF(c0_, buf_)                                                             \
  {                                                                                   \
    _Pragma("unroll") for (int j = 0; j < 4; j++) {                                   \
      int gr = (c0_) + srow + 2 * j;                                                  \
      gr = gr < C_N ? gr : (C_N - 1); /* clamp pad rows: no OOB fault */              \
      gl_lds16(proxies + (size_t)gr * D_N + scol,                                     \
               &fP[buf_][(8 * w + 2 * j) * D_N]);                                     \
    }                                                                                 \
  }

  // convert-pass geometry: thread handles row cr=t>>3, cols 16*cs..16*cs+15
  const int cr = t >> 3;
  const int cs = t & 7;

  // contiguous chunk range: block i -> start 6i+min(i,27), count 6+(i<27)
  const int bid = blockIdx.x;
  const int start = bid * 6 + (bid < 27 ? bid : 27);
  const int nch = 6 + (bid < 27 ? 1 : 0);

  STAGEF(start * 64, 0);
  int fbuf = 0, sbuf = 0;
  for (int k = 0; k < nch; k++) {
    const int cc = start + k;
    if (k + 1 < nch) {
      STAGEF((cc + 1) * 64, fbuf ^ 1);     // issue next-buffer DMA early
      __builtin_amdgcn_sched_barrier(0);   // keep stage issue above the wait
      __builtin_amdgcn_s_waitcnt(0x0F74);  // vmcnt<=4: current landed, next in flight
    } else {
      __builtin_amdgcn_sched_barrier(0);
      __builtin_amdgcn_s_waitcnt(0x0F70);  // last chunk: drain
    }
    __builtin_amdgcn_sched_barrier(0);

    // ---- wave-local normalize + bf16 convert into swizzled sP[sbuf] ----
    // (fP rows 8w..8w+7 were staged by THIS wave.)
    {
      const float* src = &fP[fbuf][cr * D_N + cs * 16];
      float4 v0 = ((const float4*)src)[0];
      float4 v1 = ((const float4*)src)[1];
      float4 v2 = ((const float4*)src)[2];
      float4 v3 = ((const float4*)src)[3];
      float s0 = v0.x * v0.x + v0.y * v0.y + v0.z * v0.z + v0.w * v0.w;
      float s1 = v1.x * v1.x + v1.y * v1.y + v1.z * v1.z + v1.w * v1.w;
      float s2 = v2.x * v2.x + v2.y * v2.y + v2.z * v2.z + v2.w * v2.w;
      float s3 = v3.x * v3.x + v3.y * v3.y + v3.z * v3.z + v3.w * v3.w;
      float ss = (s0 + s1) + (s2 + s3);  // balanced tree: matches old kA bit-exactly
      ss += __shfl_xor(ss, 1);
      ss += __shfl_xor(ss, 2);
      ss += __shfl_xor(ss, 4);
      float inv = 1.f / fmaxf(sqrtf(ss), 1e-12f);
      if (cc * 64 + cr >= C_N) inv = 0.f;  // pad rows -> exact zero vectors
      uint4 g0, g1;
      g0.x = pk2bf(v0.x * inv, v0.y * inv);
      g0.y = pk2bf(v0.z * inv, v0.w * inv);
      g0.z = pk2bf(v1.x * inv, v1.y * inv);
      g0.w = pk2bf(v1.z * inv, v1.w * inv);
      g1.x = pk2bf(v2.x * inv, v2.y * inv);
      g1.y = pk2bf(v2.z * inv, v2.w * inv);
      g1.z = pk2bf(v3.x * inv, v3.y * inv);
      g1.w = pk2bf(v3.z * inv, v3.w * inv);
      int P0 = (2 * cs) ^ (cr & 15);      // bank swizzle: phys granule = logical ^ (row&15)
      int P1 = (2 * cs + 1) ^ (cr & 15);
      *(uint4*)&sP[sbuf][cr * D_N + P0 * 8] = g0;
      *(uint4*)&sP[sbuf][cr * D_N + P1 * 8] = g1;
    }
    __builtin_amdgcn_s_waitcnt(0xC07F);  // lgkmcnt(0): own ds ops drained
    __builtin_amdgcn_s_barrier();        // sP[sbuf] tile ready for all waves
    __builtin_amdgcn_sched_barrier(0);   // no ds_read hoist above barrier

    // ---- per-nt pipeline: ds_reads -> MFMA -> exp epilogue, 4x ----
#pragma unroll
    for (int nt = 0; nt < 4; nt++) {
      short8 bfr[4];
#pragma unroll
      for (int ks = 0; ks < 4; ks++) {
        int R = 16 * nt + lc;
        int g = (ks * 4 + q) ^ lc;  // R&15 == lc
        bfr[ks] = *(const short8*)(&sP[sbuf][R * 128 + (g << 3)]);
      }
      f32x4 acc[4];
#pragma unroll
      for (int mt = 0; mt < 4; mt++) acc[mt] = (f32x4){0.f, 0.f, 0.f, 0.f};
#pragma unroll
      for (int ks = 0; ks < 4; ks++)
#pragma unroll
        for (int mt = 0; mt < 4; mt++)
          acc[mt] = __builtin_amdgcn_mfma_f32_16x16x32_bf16(afr[mt][ks], bfr[ks],
                                                            acc[mt], 0, 0, 0);
      // exp(min(6a-18,0)) == exp2(min((6*log2e)a - 18*log2e, 0)), log2e in FMA.
#pragma unroll
      for (int mt = 0; mt < 4; mt++)
#pragma unroll
        for (int r = 0; r < 4; r++)
          pe[mt][r] += __builtin_amdgcn_exp2f(
              fminf(__fmaf_rn(8.65617024533378f, acc[mt][r], -25.9685107360013f), 0.f));
    }
    // no release barrier: next convert targets sP[sbuf^1]; two-iter reuse of
    // sP[sbuf] is fenced by each wave's lgkmcnt(0)+barrier (see header note).
    fbuf ^= 1;
    sbuf ^= 1;
  }

  // reduce over 16 col-lanes; one padded atomic per row
#pragma unroll
  for (int mt = 0; mt < 4; mt++) {
#pragma unroll
    for (int r = 0; r < 4; r++) {
      float p = pe[mt][r];
      p += __shfl_xor(p, 1);
      p += __shfl_xor(p, 2);
      p += __shfl_xor(p, 4);
      p += __shfl_xor(p, 8);
      if (lc == 0) {
        int rb = 64 * w + 16 * mt + 4 * q + r;
        atomicAdd(&sumexpP[rb * 16], p);
      }
    }
  }

  // fused k7: last block to arrive reduces the loss. Atomics complete at the
  // device coherence point; ordering needs only vmcnt(0) (NO threadfence --
  // agent fences emit L2 writeback/invalidate, measured ~46 us over the grid).
  __builtin_amdgcn_s_waitcnt(0);
  if (t == 0) sLast = atomicAdd(&ctrs[32], 1);
  __syncthreads();
  if (sLast == K6_BLOCKS - 1) {
    float se = __hip_atomic_load(&sumexpP[t * 16], __ATOMIC_RELAXED,
                                 __HIP_MEMORY_SCOPE_AGENT);
    float v = lossT[t] + logf(se - PAD_CORR);
    float s = block_reduce_sum<512>(v, redf);
    if (t == 0) out[0] = s * (1.0f / 512.0f);
  }
}

extern "C" void kernel_launch(void* const* d_in, const int* in_sizes, int n_in,
                              void* d_out, int out_size, void* d_ws, size_t ws_size,
                              hipStream_t stream) {
  const float* X = (const float*)d_in[0];
  const int* T = (const int*)d_in[2];
  const float* proxies = (const float*)d_in[3];
  float* out = (float*)d_out;

  char* ws = (char*)d_ws;
  // (Pnb region retired -- offsets kept identical for layout stability)
  float* Xn = (float*)(ws + (size_t)CPAD * D_N * 2);       // 512*128
  float* Pb = Xn + B_N * D_N;                              // 512*128
  float* X2 = Pb + B_N * D_N;                              // 512*128 (unused, layout kept)
  float* dg = X2 + B_N * D_N;                              // 512
  float* S = dg + B_N;                                     // 512
  float* lossT = S + B_N;                                  // 512
  float* sumexpP = lossT + B_N;                            // 512*16 (line-padded)
  unsigned short* Xsb = (unsigned short*)(sumexpP + B_N * 16);  // 512*128 bf16
  float* A = (float*)(Xsb + B_N * D_N);                    // 512*512
  int* ctrs = (int*)(A + B_N * B_N);                       // [32] = k6 arrive counter

  kX<<<B_N, 128, 0, stream>>>(X, proxies, T, Xn, Pb, dg, ctrs);
  k3_att<<<B_N, 512, 0, stream>>>(Xn, Pb, dg, A, S);
  k4ab<<<B_N, 512, 0, stream>>>(Xn, Pb, A, S, Xsb, lossT, sumexpP);
  k6_big<<<K6_GX, 512, 0, stream>>>(proxies, Xsb, sumexpP, lossT, ctrs, out);
}